// Round 4
// baseline (306.691 us; speedup 1.0000x reference)
//
#include <hip/hip_runtime.h>
#include <hip/hip_bf16.h>
#include <math.h>

// Problem constants (from reference)
#define N_NODES 50000
#define N_EDGES 800000
#define E_TOT   (N_EDGES + N_NODES)   // edges + self loops = 850000
#define HID     128
#define N_GRAPHS 64
#define NEG_SLOPE 0.2f

// Radix partition params
#define NBKT 196                      // buckets of 256 dst nodes
#define CAPB 6144                     // fixed bucket capacity (mean 4337, +27 sigma)
#define CHUNK3 4096
#define NB3  ((E_TOT + CHUNK3 - 1) / CHUNK3)    // 208

typedef __attribute__((ext_vector_type(8))) short bf16x8;
typedef __attribute__((ext_vector_type(4))) float f32x4;

__device__ __forceinline__ ushort f2bf(float f) {
    union { float f; uint u; } x; x.f = f;
    uint r = x.u + 0x7fffu + ((x.u >> 16) & 1u);   // round-to-nearest-even
    return (ushort)(r >> 16);
}
__device__ __forceinline__ float bfbits2f(uint bits_hi) {
    union { uint u; float f; } x; x.u = bits_hi;
    return x.f;
}

// ---------------------------------------------------------------------------
// P3: block-local bucket ordering in LDS, coalesced run writes into
// fixed-capacity bucket slots. val = bucket(8) | src(16) | dst&255 (8).
// ---------------------------------------------------------------------------
__global__ __launch_bounds__(256) void bin_scatter(const int* __restrict__ edge_src,
                                                   const int* __restrict__ edge_dst,
                                                   int* __restrict__ gcur,
                                                   uint* __restrict__ staged) {
    __shared__ int hist[256], scan_s[256], base_l[256], cur[256], runbase[256];
    __shared__ uint vals[CHUNK3];
    int tid = threadIdx.x;
    int e0 = blockIdx.x * CHUNK3;
    int cnt = min(CHUNK3, E_TOT - e0);

    hist[tid] = 0;
    __syncthreads();
    for (int i = tid; i < cnt; i += 256) {
        int e = e0 + i;
        int d = (e < N_EDGES) ? edge_dst[e] : (e - N_EDGES);
        atomicAdd(&hist[d >> 8], 1);
    }
    __syncthreads();
    int v = hist[tid];
    scan_s[tid] = v;
    __syncthreads();
    for (int off = 1; off < 256; off <<= 1) {
        int t = (tid >= off) ? scan_s[tid - off] : 0;
        __syncthreads();
        scan_s[tid] += t;
        __syncthreads();
    }
    base_l[tid] = scan_s[tid] - v;
    cur[tid] = scan_s[tid] - v;
    __syncthreads();
    for (int i = tid; i < cnt; i += 256) {
        int e = e0 + i;
        int s, d;
        if (e < N_EDGES) { s = edge_src[e]; d = edge_dst[e]; }
        else             { s = d = e - N_EDGES; }
        int p = atomicAdd(&cur[d >> 8], 1);
        vals[p] = ((uint)(d >> 8) << 24) | ((uint)s << 8) | (uint)(d & 255);
    }
    __syncthreads();
    if (tid < NBKT && hist[tid] > 0) runbase[tid] = atomicAdd(&gcur[tid], hist[tid]);
    __syncthreads();
    for (int i = tid; i < cnt; i += 256) {
        uint v2 = vals[i];
        int b = (int)(v2 >> 24);
        int idx = runbase[b] + (i - base_l[b]);
        if (idx < CAPB) staged[b * CAPB + idx] = v2;
    }
}

// ---------------------------------------------------------------------------
// Scan bucket counts -> bucket bases (global CSR offsets)
// ---------------------------------------------------------------------------
__global__ __launch_bounds__(256) void bucket_scan(const int* __restrict__ gcur,
                                                   int* __restrict__ bbase,
                                                   int* __restrict__ row_start) {
    __shared__ int s[256];
    int tid = threadIdx.x;
    int v = (tid < NBKT) ? gcur[tid] : 0;
    s[tid] = v;
    __syncthreads();
    for (int off = 1; off < 256; off <<= 1) {
        int t = (tid >= off) ? s[tid - off] : 0;
        __syncthreads();
        s[tid] += t;
        __syncthreads();
    }
    if (tid < NBKT) bbase[tid] = s[tid] - v;
    if (tid == 255) { bbase[NBKT] = s[255]; row_start[N_NODES] = s[255]; }
}

// ---------------------------------------------------------------------------
// P4: one block per bucket; exact per-node CSR (ushort src) + row_start
// ---------------------------------------------------------------------------
__global__ __launch_bounds__(256) void bucket_build(const uint* __restrict__ staged,
                                                    const int* __restrict__ bbase,
                                                    int* __restrict__ row_start,
                                                    ushort* __restrict__ csr_src) {
    __shared__ int hist[256], scan_s[256], base_l[256];
    __shared__ uint lv[CAPB];
    int tid = threadIdx.x;
    int b = blockIdx.x;
    int base = bbase[b];
    int cnt = bbase[b + 1] - base;

    hist[tid] = 0;
    __syncthreads();
    for (int i = tid; i < cnt; i += 256) {
        uint v = staged[b * CAPB + i];
        lv[i] = v;
        atomicAdd(&hist[v & 255], 1);
    }
    __syncthreads();
    int v0 = hist[tid];
    scan_s[tid] = v0;
    __syncthreads();
    for (int off = 1; off < 256; off <<= 1) {
        int t = (tid >= off) ? scan_s[tid - off] : 0;
        __syncthreads();
        scan_s[tid] += t;
        __syncthreads();
    }
    int excl = scan_s[tid] - v0;
    base_l[tid] = excl;
    int node = b * 256 + tid;
    if (node < N_NODES) row_start[node] = base + excl;
    __syncthreads();
    for (int i = tid; i < cnt; i += 256) {
        uint v = lv[i];
        int pos = base + atomicAdd(&base_l[v & 255], 1);
        csr_src[pos] = (ushort)((v >> 8) & 0xFFFFu);
    }
}

// Graph boundaries from sorted batch array (handles empty graphs)
__global__ void graph_bounds(const int* __restrict__ batch, int* __restrict__ gstart) {
    int i = blockIdx.x * blockDim.x + threadIdx.x;
    if (i >= N_NODES) return;
    int b  = batch[i];
    int bp = (i == 0) ? -1 : batch[i - 1];
    for (int g = bp + 1; g <= b; g++) gstart[g] = i;
    if (i == N_NODES - 1) {
        for (int g = b + 1; g <= N_GRAPHS; g++) gstart[g] = N_NODES;
    }
}

// Transpose + convert weights: W[K][128] fp32 -> Wt[128][K] bf16
template <int K>
__global__ void convW(const float* __restrict__ W, ushort* __restrict__ Wt) {
    int idx = blockIdx.x * 256 + threadIdx.x;
    if (idx >= K * 128) return;
    int k = idx >> 7, n = idx & 127;
    Wt[n * K + k] = f2bf(W[idx]);
}

// ---------------------------------------------------------------------------
// BF16 MFMA GEMM + fused alpha epilogue.
// ---------------------------------------------------------------------------
template <int K, bool ABF>
__global__ __launch_bounds__(256) void gemm_mfma(const void* __restrict__ Aptr,
                                                 const ushort* __restrict__ Wt,
                                                 ushort* __restrict__ Cbf,
                                                 const float* __restrict__ a_sv,
                                                 const float* __restrict__ a_dv,
                                                 float* __restrict__ alpha_s,
                                                 float* __restrict__ alpha_d, int M) {
    constexpr int KC = 64;
    constexpr int AP = 72;
    __shared__ ushort As[64 * AP];
    __shared__ ushort Bs[128 * AP];

    int tid = threadIdx.x;
    int lane = tid & 63;
    int wv = tid >> 6;
    int mrow = lane & 15;
    int quad = lane >> 4;
    int row0 = blockIdx.x * 64;

    f32x4 acc[8];
#pragma unroll
    for (int t = 0; t < 8; t++) acc[t] = (f32x4){0.f, 0.f, 0.f, 0.f};

    for (int k0 = 0; k0 < K; k0 += KC) {
        if constexpr (!ABF) {
            const float* A = (const float*)Aptr;
#pragma unroll
            for (int p = 0; p < 2; p++) {
                int c = p * 256 + tid;
                int r = c >> 3;
                int kk = (c & 7) * 8;
                int grow = row0 + r;
                float4 v0 = make_float4(0.f, 0.f, 0.f, 0.f);
                float4 v1 = v0;
                if (grow < M) {
                    const float* src = &A[(size_t)grow * K + k0 + kk];
                    v0 = *(const float4*)src;
                    v1 = *(const float4*)(src + 4);
                }
                uint4 w;
                w.x = (uint)f2bf(v0.x) | ((uint)f2bf(v0.y) << 16);
                w.y = (uint)f2bf(v0.z) | ((uint)f2bf(v0.w) << 16);
                w.z = (uint)f2bf(v1.x) | ((uint)f2bf(v1.y) << 16);
                w.w = (uint)f2bf(v1.z) | ((uint)f2bf(v1.w) << 16);
                *(uint4*)&As[r * AP + kk] = w;
            }
        } else {
            const ushort* A = (const ushort*)Aptr;
#pragma unroll
            for (int p = 0; p < 2; p++) {
                int c = p * 256 + tid;
                int r = c >> 3;
                int kk = (c & 7) * 8;
                int grow = row0 + r;
                uint4 v = make_uint4(0, 0, 0, 0);
                if (grow < M) v = *(const uint4*)&A[(size_t)grow * K + k0 + kk];
                *(uint4*)&As[r * AP + kk] = v;
            }
        }
#pragma unroll
        for (int p = 0; p < 4; p++) {
            int c = p * 256 + tid;
            int n = c >> 3;
            int kk = (c & 7) * 8;
            uint4 v = *(const uint4*)&Wt[(size_t)n * K + k0 + kk];
            *(uint4*)&Bs[n * AP + kk] = v;
        }
        __syncthreads();

        const ushort* arow = &As[(wv * 16 + mrow) * AP + quad * 8];
        const ushort* brow = &Bs[mrow * AP + quad * 8];
#pragma unroll
        for (int ks = 0; ks < KC; ks += 32) {
            bf16x8 a = *(const bf16x8*)&arow[ks];
#pragma unroll
            for (int t = 0; t < 8; t++) {
                bf16x8 b = *(const bf16x8*)&brow[t * 16 * AP + ks];
                acc[t] = __builtin_amdgcn_mfma_f32_16x16x32_bf16(a, b, acc[t], 0, 0, 0);
            }
        }
        __syncthreads();
    }

    // Fused alpha epilogue
    float as_r[8], ad_r[8];
#pragma unroll
    for (int t = 0; t < 8; t++) {
        int col = t * 16 + mrow;
        as_r[t] = a_sv[col];
        ad_r[t] = a_dv[col];
    }
#pragma unroll
    for (int r = 0; r < 4; r++) {
        float ps = 0.f, pd = 0.f;
#pragma unroll
        for (int t = 0; t < 8; t++) {
            ps = fmaf(acc[t][r], as_r[t], ps);
            pd = fmaf(acc[t][r], ad_r[t], pd);
        }
#pragma unroll
        for (int o = 1; o < 16; o <<= 1) {
            ps += __shfl_xor(ps, o, 64);
            pd += __shfl_xor(pd, o, 64);
        }
        int row = row0 + wv * 16 + quad * 4 + r;
        if (mrow == 0 && row < M) {
            alpha_s[row] = ps;
            alpha_d[row] = pd;
        }
    }

    // C write (C/D layout: col=lane&15, row=quad*4+reg)
#pragma unroll
    for (int t = 0; t < 8; t++) {
#pragma unroll
        for (int r = 0; r < 4; r++) {
            int row = row0 + wv * 16 + quad * 4 + r;
            if (row < M)
                Cbf[(size_t)row * HID + t * 16 + mrow] = f2bf(acc[t][r]);
        }
    }
}

// ---------------------------------------------------------------------------
// GAT aggregation: 4 nodes/block, one wave per node, barrier-free (shfl
// broadcast), single alpha sweep (no max subtraction - shift invariant),
// chunk-0 exp cached in registers. bf16 gathers + bf16 output.
// ---------------------------------------------------------------------------
__global__ __launch_bounds__(256) void gat_aggregate(const ushort* __restrict__ hbf,
                                                     const float* __restrict__ alpha_s,
                                                     const float* __restrict__ alpha_d,
                                                     const int* __restrict__ row_start,
                                                     const ushort* __restrict__ csr_src,
                                                     const float* __restrict__ bias,
                                                     ushort* __restrict__ outbf) {
    int wv = threadIdx.x >> 6;
    int lane = threadIdx.x & 63;
    int n = blockIdx.x * 4 + wv;
    if (n >= N_NODES) return;
    int beg = row_start[n];
    int deg = row_start[n + 1] - beg;
    float adn = alpha_d[n];

    // Sweep 1: per-lane exp(leaky(e)); chunk 0 cached in registers
    float ex0 = 0.f;
    int s0 = 0;
    if (lane < deg) {
        s0 = csr_src[beg + lane];
        float e = alpha_s[s0] + adn;
        e = (e > 0.f) ? e : e * NEG_SLOPE;
        ex0 = __expf(e);
    }
    float ssum = ex0;
    for (int k = 64 + lane; k < deg; k += 64) {
        int s = csr_src[beg + k];
        float e = alpha_s[s] + adn;
        e = (e > 0.f) ? e : e * NEG_SLOPE;
        ssum += __expf(e);
    }
    for (int o = 32; o; o >>= 1) ssum += __shfl_xor(ssum, o, 64);
    float inv = 1.f / ssum;
    ex0 *= inv;

    // Sweep 2: weighted aggregate; lane owns cols 2*lane, 2*lane+1
    float acc0 = 0.f, acc1 = 0.f;
    int cnt = min(64, deg);
#pragma unroll 4
    for (int j = 0; j < cnt; j++) {
        float w = __shfl(ex0, j, 64);
        int sj = __shfl(s0, j, 64);
        uint v = *(const uint*)&hbf[(size_t)sj * HID + 2 * lane];
        acc0 = fmaf(w, bfbits2f(v << 16), acc0);
        acc1 = fmaf(w, bfbits2f(v & 0xffff0000u), acc1);
    }
    for (int c0 = 64; c0 < deg; c0 += 64) {
        int k = c0 + lane;
        float cf = 0.f;
        int s = 0;
        if (k < deg) {
            s = csr_src[beg + k];
            float e = alpha_s[s] + adn;
            e = (e > 0.f) ? e : e * NEG_SLOPE;
            cf = __expf(e) * inv;
        }
        int c2 = min(64, deg - c0);
        for (int j = 0; j < c2; j++) {
            float w = __shfl(cf, j, 64);
            int sj = __shfl(s, j, 64);
            uint v = *(const uint*)&hbf[(size_t)sj * HID + 2 * lane];
            acc0 = fmaf(w, bfbits2f(v << 16), acc0);
            acc1 = fmaf(w, bfbits2f(v & 0xffff0000u), acc1);
        }
    }
    float2 bv = *(const float2*)&bias[2 * lane];
    float o0 = fmaxf(acc0 + bv.x, 0.f);
    float o1 = fmaxf(acc1 + bv.y, 0.f);
    uint pk = (uint)f2bf(o0) | ((uint)f2bf(o1) << 16);
    *(uint*)&outbf[(size_t)n * HID + 2 * lane] = pk;
}

// ---------------------------------------------------------------------------
// Mean pool per graph (two-stage, bf16 input) + classifier
// ---------------------------------------------------------------------------
__global__ __launch_bounds__(128) void pool_partial(const ushort* __restrict__ h,
                                                    const int* __restrict__ gstart,
                                                    float* __restrict__ pool) {
    int g = blockIdx.x;
    int slice = blockIdx.y;
    int d = threadIdx.x;
    int beg = gstart[g], end = gstart[g + 1];
    float acc = 0.f;
    for (int i = beg + slice; i < end; i += 16)
        acc += bfbits2f(((uint)h[(size_t)i * HID + d]) << 16);
    atomicAdd(&pool[g * HID + d], acc);
}

__global__ __launch_bounds__(128) void classify(const float* __restrict__ pool,
                                                const int* __restrict__ gstart,
                                                const float* __restrict__ Wc,
                                                const float* __restrict__ bc,
                                                float* __restrict__ out) {
    int g = blockIdx.x;
    int d = threadIdx.x;
    float cnt = (float)(gstart[g + 1] - gstart[g]);
    float pooled = pool[g * HID + d] / fmaxf(cnt, 1.f);
    float p = pooled * Wc[d];
    __shared__ float red[2];
    for (int o = 32; o; o >>= 1) p += __shfl_xor(p, o, 64);
    if ((d & 63) == 0) red[d >> 6] = p;
    __syncthreads();
    if (d == 0) {
        float t = red[0] + red[1] + bc[0];
        out[g] = 1.f / (1.f + expf(-t));
    }
}

// ---------------------------------------------------------------------------
extern "C" void kernel_launch(void* const* d_in, const int* in_sizes, int n_in,
                              void* d_out, int out_size, void* d_ws, size_t ws_size,
                              hipStream_t stream) {
    const float* x     = (const float*)d_in[0];
    const int*   ei    = (const int*)d_in[1];
    const int*   batch = (const int*)d_in[2];
    const float* W1    = (const float*)d_in[3];
    const float* as1   = (const float*)d_in[4];
    const float* ad1   = (const float*)d_in[5];
    const float* b1    = (const float*)d_in[6];
    const float* W2    = (const float*)d_in[7];
    const float* as2   = (const float*)d_in[8];
    const float* ad2   = (const float*)d_in[9];
    const float* b2    = (const float*)d_in[10];
    const float* Wc    = (const float*)d_in[11];
    const float* bc    = (const float*)d_in[12];
    float* out = (float*)d_out;

    char* p = (char*)d_ws;
    auto alloc = [&](size_t bytes) {
        void* r = (void*)p;
        p += (bytes + 255) & ~(size_t)255;
        return r;
    };
    ushort* h0     = (ushort*)alloc((size_t)N_NODES * HID * 2);   // gemm1 out / agg2 out
    ushort* h1     = (ushort*)alloc((size_t)N_NODES * HID * 2);   // agg1 out
    ushort* h2     = (ushort*)alloc((size_t)N_NODES * HID * 2);   // gemm2 out
    float*  alS    = (float*)alloc((size_t)N_NODES * 4);
    float*  alD    = (float*)alloc((size_t)N_NODES * 4);
    uint*   staged = (uint*)alloc((size_t)NBKT * CAPB * 4);       // 4.8 MB
    ushort* csr    = (ushort*)alloc((size_t)E_TOT * 2);           // 1.7 MB
    int*    rstart = (int*)alloc((size_t)(N_NODES + 1) * 4);
    int*    bbase  = (int*)alloc((NBKT + 1) * 4);
    int*    gcur   = (int*)alloc((NBKT + 1) * 4);
    int*    gstart = (int*)alloc((N_GRAPHS + 1) * 4);
    float*  pool   = (float*)alloc(N_GRAPHS * HID * 4);
    ushort* Wt1    = (ushort*)alloc((size_t)128 * 256 * 2);
    ushort* Wt2    = (ushort*)alloc((size_t)128 * 128 * 2);

    const int* edge_src = ei;
    const int* edge_dst = ei + N_EDGES;

    hipMemsetAsync(gcur, 0, (NBKT + 1) * 4, stream);
    hipMemsetAsync(pool, 0, (size_t)N_GRAPHS * HID * 4, stream);

    // Weight prep + radix-partition CSR build
    convW<256><<<(256 * 128 + 255) / 256, 256, 0, stream>>>(W1, Wt1);
    convW<128><<<(128 * 128 + 255) / 256, 256, 0, stream>>>(W2, Wt2);
    bin_scatter<<<NB3, 256, 0, stream>>>(edge_src, edge_dst, gcur, staged);
    bucket_scan<<<1, 256, 0, stream>>>(gcur, bbase, rstart);
    bucket_build<<<NBKT, 256, 0, stream>>>(staged, bbase, rstart, csr);
    graph_bounds<<<(N_NODES + 255) / 256, 256, 0, stream>>>(batch, gstart);

    // Layer 1
    gemm_mfma<256, false><<<(N_NODES + 63) / 64, 256, 0, stream>>>(
        x, Wt1, h0, as1, ad1, alS, alD, N_NODES);
    gat_aggregate<<<(N_NODES + 3) / 4, 256, 0, stream>>>(h0, alS, alD, rstart, csr, b1, h1);

    // Layer 2
    gemm_mfma<128, true><<<(N_NODES + 63) / 64, 256, 0, stream>>>(
        h1, Wt2, h2, as2, ad2, alS, alD, N_NODES);
    gat_aggregate<<<(N_NODES + 3) / 4, 256, 0, stream>>>(h2, alS, alD, rstart, csr, b2, h0);

    // Pool + classify
    pool_partial<<<dim3(N_GRAPHS, 16), HID, 0, stream>>>(h0, gstart, pool);
    classify<<<N_GRAPHS, HID, 0, stream>>>(pool, gstart, Wc, bc, out);
}

// Round 5
// 270.276 us; speedup vs baseline: 1.1347x; 1.1347x over previous
//
#include <hip/hip_runtime.h>
#include <hip/hip_bf16.h>
#include <math.h>

// Problem constants (from reference)
#define N_NODES 50000
#define N_EDGES 800000
#define E_TOT   (N_EDGES + N_NODES)   // edges + self loops = 850000
#define HID     128
#define N_GRAPHS 64
#define NEG_SLOPE 0.2f

// Radix partition params
#define NBKT 196                      // buckets of 256 dst nodes
#define CAPB 6144                     // fixed bucket capacity (mean 4337, +27 sigma)
#define CHUNK3 4096
#define NB3  ((E_TOT + CHUNK3 - 1) / CHUNK3)    // 208

typedef __attribute__((ext_vector_type(8))) short bf16x8;
typedef __attribute__((ext_vector_type(4))) float f32x4;

__device__ __forceinline__ ushort f2bf(float f) {
    union { float f; uint u; } x; x.f = f;
    uint r = x.u + 0x7fffu + ((x.u >> 16) & 1u);   // round-to-nearest-even
    return (ushort)(r >> 16);
}
__device__ __forceinline__ float bfbits2f(uint bits_hi) {
    union { uint u; float f; } x; x.u = bits_hi;
    return x.f;
}

// ---------------------------------------------------------------------------
// P3: block-local bucket ordering in LDS, coalesced run writes into
// fixed-capacity bucket slots. val = bucket(8) | src(16) | dst&255 (8).
// ---------------------------------------------------------------------------
__global__ __launch_bounds__(256) void bin_scatter(const int* __restrict__ edge_src,
                                                   const int* __restrict__ edge_dst,
                                                   int* __restrict__ gcur,
                                                   uint* __restrict__ staged) {
    __shared__ int hist[256], scan_s[256], base_l[256], cur[256], runbase[256];
    __shared__ uint vals[CHUNK3];
    int tid = threadIdx.x;
    int e0 = blockIdx.x * CHUNK3;
    int cnt = min(CHUNK3, E_TOT - e0);

    hist[tid] = 0;
    __syncthreads();
    for (int i = tid; i < cnt; i += 256) {
        int e = e0 + i;
        int d = (e < N_EDGES) ? edge_dst[e] : (e - N_EDGES);
        atomicAdd(&hist[d >> 8], 1);
    }
    __syncthreads();
    int v = hist[tid];
    scan_s[tid] = v;
    __syncthreads();
    for (int off = 1; off < 256; off <<= 1) {
        int t = (tid >= off) ? scan_s[tid - off] : 0;
        __syncthreads();
        scan_s[tid] += t;
        __syncthreads();
    }
    base_l[tid] = scan_s[tid] - v;
    cur[tid] = scan_s[tid] - v;
    __syncthreads();
    for (int i = tid; i < cnt; i += 256) {
        int e = e0 + i;
        int s, d;
        if (e < N_EDGES) { s = edge_src[e]; d = edge_dst[e]; }
        else             { s = d = e - N_EDGES; }
        int p = atomicAdd(&cur[d >> 8], 1);
        vals[p] = ((uint)(d >> 8) << 24) | ((uint)s << 8) | (uint)(d & 255);
    }
    __syncthreads();
    if (tid < NBKT && hist[tid] > 0) runbase[tid] = atomicAdd(&gcur[tid], hist[tid]);
    __syncthreads();
    for (int i = tid; i < cnt; i += 256) {
        uint v2 = vals[i];
        int b = (int)(v2 >> 24);
        int idx = runbase[b] + (i - base_l[b]);
        if (idx < CAPB) staged[b * CAPB + idx] = v2;
    }
}

// ---------------------------------------------------------------------------
// Scan bucket counts -> bucket bases (global CSR offsets)
// ---------------------------------------------------------------------------
__global__ __launch_bounds__(256) void bucket_scan(const int* __restrict__ gcur,
                                                   int* __restrict__ bbase,
                                                   int* __restrict__ row_start) {
    __shared__ int s[256];
    int tid = threadIdx.x;
    int v = (tid < NBKT) ? gcur[tid] : 0;
    s[tid] = v;
    __syncthreads();
    for (int off = 1; off < 256; off <<= 1) {
        int t = (tid >= off) ? s[tid - off] : 0;
        __syncthreads();
        s[tid] += t;
        __syncthreads();
    }
    if (tid < NBKT) bbase[tid] = s[tid] - v;
    if (tid == 255) { bbase[NBKT] = s[255]; row_start[N_NODES] = s[255]; }
}

// ---------------------------------------------------------------------------
// P4: one block per bucket; exact per-node CSR (ushort src) + row_start
// ---------------------------------------------------------------------------
__global__ __launch_bounds__(256) void bucket_build(const uint* __restrict__ staged,
                                                    const int* __restrict__ bbase,
                                                    int* __restrict__ row_start,
                                                    ushort* __restrict__ csr_src) {
    __shared__ int hist[256], scan_s[256], base_l[256];
    __shared__ uint lv[CAPB];
    int tid = threadIdx.x;
    int b = blockIdx.x;
    int base = bbase[b];
    int cnt = bbase[b + 1] - base;

    hist[tid] = 0;
    __syncthreads();
    for (int i = tid; i < cnt; i += 256) {
        uint v = staged[b * CAPB + i];
        lv[i] = v;
        atomicAdd(&hist[v & 255], 1);
    }
    __syncthreads();
    int v0 = hist[tid];
    scan_s[tid] = v0;
    __syncthreads();
    for (int off = 1; off < 256; off <<= 1) {
        int t = (tid >= off) ? scan_s[tid - off] : 0;
        __syncthreads();
        scan_s[tid] += t;
        __syncthreads();
    }
    int excl = scan_s[tid] - v0;
    base_l[tid] = excl;
    int node = b * 256 + tid;
    if (node < N_NODES) row_start[node] = base + excl;
    __syncthreads();
    for (int i = tid; i < cnt; i += 256) {
        uint v = lv[i];
        int pos = base + atomicAdd(&base_l[v & 255], 1);
        csr_src[pos] = (ushort)((v >> 8) & 0xFFFFu);
    }
}

// Graph boundaries from sorted batch array (handles empty graphs)
__global__ void graph_bounds(const int* __restrict__ batch, int* __restrict__ gstart) {
    int i = blockIdx.x * blockDim.x + threadIdx.x;
    if (i >= N_NODES) return;
    int b  = batch[i];
    int bp = (i == 0) ? -1 : batch[i - 1];
    for (int g = bp + 1; g <= b; g++) gstart[g] = i;
    if (i == N_NODES - 1) {
        for (int g = b + 1; g <= N_GRAPHS; g++) gstart[g] = N_NODES;
    }
}

// Transpose + convert weights: W[K][128] fp32 -> Wt[128][K] bf16
template <int K>
__global__ void convW(const float* __restrict__ W, ushort* __restrict__ Wt) {
    int idx = blockIdx.x * 256 + threadIdx.x;
    if (idx >= K * 128) return;
    int k = idx >> 7, n = idx & 127;
    Wt[n * K + k] = f2bf(W[idx]);
}

// ---------------------------------------------------------------------------
// BF16 MFMA GEMM + fused alpha epilogue.
// ---------------------------------------------------------------------------
template <int K, bool ABF>
__global__ __launch_bounds__(256) void gemm_mfma(const void* __restrict__ Aptr,
                                                 const ushort* __restrict__ Wt,
                                                 ushort* __restrict__ Cbf,
                                                 const float* __restrict__ a_sv,
                                                 const float* __restrict__ a_dv,
                                                 float* __restrict__ alpha_s,
                                                 float* __restrict__ alpha_d, int M) {
    constexpr int KC = 64;
    constexpr int AP = 72;
    __shared__ ushort As[64 * AP];
    __shared__ ushort Bs[128 * AP];

    int tid = threadIdx.x;
    int lane = tid & 63;
    int wv = tid >> 6;
    int mrow = lane & 15;
    int quad = lane >> 4;
    int row0 = blockIdx.x * 64;

    f32x4 acc[8];
#pragma unroll
    for (int t = 0; t < 8; t++) acc[t] = (f32x4){0.f, 0.f, 0.f, 0.f};

    for (int k0 = 0; k0 < K; k0 += KC) {
        if constexpr (!ABF) {
            const float* A = (const float*)Aptr;
#pragma unroll
            for (int p = 0; p < 2; p++) {
                int c = p * 256 + tid;
                int r = c >> 3;
                int kk = (c & 7) * 8;
                int grow = row0 + r;
                float4 v0 = make_float4(0.f, 0.f, 0.f, 0.f);
                float4 v1 = v0;
                if (grow < M) {
                    const float* src = &A[(size_t)grow * K + k0 + kk];
                    v0 = *(const float4*)src;
                    v1 = *(const float4*)(src + 4);
                }
                uint4 w;
                w.x = (uint)f2bf(v0.x) | ((uint)f2bf(v0.y) << 16);
                w.y = (uint)f2bf(v0.z) | ((uint)f2bf(v0.w) << 16);
                w.z = (uint)f2bf(v1.x) | ((uint)f2bf(v1.y) << 16);
                w.w = (uint)f2bf(v1.z) | ((uint)f2bf(v1.w) << 16);
                *(uint4*)&As[r * AP + kk] = w;
            }
        } else {
            const ushort* A = (const ushort*)Aptr;
#pragma unroll
            for (int p = 0; p < 2; p++) {
                int c = p * 256 + tid;
                int r = c >> 3;
                int kk = (c & 7) * 8;
                int grow = row0 + r;
                uint4 v = make_uint4(0, 0, 0, 0);
                if (grow < M) v = *(const uint4*)&A[(size_t)grow * K + k0 + kk];
                *(uint4*)&As[r * AP + kk] = v;
            }
        }
#pragma unroll
        for (int p = 0; p < 4; p++) {
            int c = p * 256 + tid;
            int n = c >> 3;
            int kk = (c & 7) * 8;
            uint4 v = *(const uint4*)&Wt[(size_t)n * K + k0 + kk];
            *(uint4*)&Bs[n * AP + kk] = v;
        }
        __syncthreads();

        const ushort* arow = &As[(wv * 16 + mrow) * AP + quad * 8];
        const ushort* brow = &Bs[mrow * AP + quad * 8];
#pragma unroll
        for (int ks = 0; ks < KC; ks += 32) {
            bf16x8 a = *(const bf16x8*)&arow[ks];
#pragma unroll
            for (int t = 0; t < 8; t++) {
                bf16x8 b = *(const bf16x8*)&brow[t * 16 * AP + ks];
                acc[t] = __builtin_amdgcn_mfma_f32_16x16x32_bf16(a, b, acc[t], 0, 0, 0);
            }
        }
        __syncthreads();
    }

    // Fused alpha epilogue
    float as_r[8], ad_r[8];
#pragma unroll
    for (int t = 0; t < 8; t++) {
        int col = t * 16 + mrow;
        as_r[t] = a_sv[col];
        ad_r[t] = a_dv[col];
    }
#pragma unroll
    for (int r = 0; r < 4; r++) {
        float ps = 0.f, pd = 0.f;
#pragma unroll
        for (int t = 0; t < 8; t++) {
            ps = fmaf(acc[t][r], as_r[t], ps);
            pd = fmaf(acc[t][r], ad_r[t], pd);
        }
#pragma unroll
        for (int o = 1; o < 16; o <<= 1) {
            ps += __shfl_xor(ps, o, 64);
            pd += __shfl_xor(pd, o, 64);
        }
        int row = row0 + wv * 16 + quad * 4 + r;
        if (mrow == 0 && row < M) {
            alpha_s[row] = ps;
            alpha_d[row] = pd;
        }
    }

    // C write (C/D layout: col=lane&15, row=quad*4+reg)
#pragma unroll
    for (int t = 0; t < 8; t++) {
#pragma unroll
        for (int r = 0; r < 4; r++) {
            int row = row0 + wv * 16 + quad * 4 + r;
            if (row < M)
                Cbf[(size_t)row * HID + t * 16 + mrow] = f2bf(acc[t][r]);
        }
    }
}

// ---------------------------------------------------------------------------
// GAT aggregation: 4 nodes/block, one wave per node (per-wave LDS segment,
// no cross-wave barriers). Single alpha sweep (shift-invariant softmax),
// chunk-0 exp cached in registers. Half-wave row pairing: 32 lanes x uint2
// cover one 256B h-row, 2 edges in flight per step; batch-8 gathers for MLP.
// ---------------------------------------------------------------------------
__global__ __launch_bounds__(256) void gat_aggregate(const ushort* __restrict__ hbf,
                                                     const float* __restrict__ alpha_s,
                                                     const float* __restrict__ alpha_d,
                                                     const int* __restrict__ row_start,
                                                     const ushort* __restrict__ csr_src,
                                                     const float* __restrict__ bias,
                                                     ushort* __restrict__ outbf) {
    __shared__ float coefs[4][64];
    __shared__ uint  soffs[4][64];     // byte offsets = src * 256
    int wv = threadIdx.x >> 6;
    int lane = threadIdx.x & 63;
    int n = blockIdx.x * 4 + wv;       // grid = N_NODES/4 exactly
    float* coef = coefs[wv];
    uint*  soff = soffs[wv];

    int beg = row_start[n];
    int deg = row_start[n + 1] - beg;
    float adn = alpha_d[n];

    // Sweep 1: denom; chunk-0 exp/src cached in registers
    float ex0 = 0.f;
    int s0r = 0;
    if (lane < deg) {
        s0r = csr_src[beg + lane];
        float e = alpha_s[s0r] + adn;
        e = (e > 0.f) ? e : e * NEG_SLOPE;
        ex0 = __expf(e);
    }
    float ssum = ex0;
    for (int k = 64 + lane; k < deg; k += 64) {
        int s = csr_src[beg + k];
        float e = alpha_s[s] + adn;
        e = (e > 0.f) ? e : e * NEG_SLOPE;
        ssum += __expf(e);
    }
    for (int o = 32; o; o >>= 1) ssum += __shfl_xor(ssum, o, 64);
    float inv = 1.f / ssum;

    int half = lane >> 5;              // 0 or 1: which edge of the pair
    int c4 = (lane & 31) * 4;          // 4 columns owned by this lane
    float a0 = 0.f, a1 = 0.f, a2 = 0.f, a3 = 0.f;
    const char* hbase = (const char*)hbf + c4 * 2;

    for (int c0 = 0; c0 < deg; c0 += 64) {
        if (c0 == 0) {
            coef[lane] = ex0 * inv;    // lanes >= deg write 0 (unused)
            soff[lane] = (uint)s0r * (HID * 2);
        } else {
            int k = c0 + lane;
            if (k < deg) {
                int s = csr_src[beg + k];
                float e = alpha_s[s] + adn;
                e = (e > 0.f) ? e : e * NEG_SLOPE;
                coef[lane] = __expf(e) * inv;
                soff[lane] = (uint)s * (HID * 2);
            }
        }
        __builtin_amdgcn_wave_barrier();
        int cnt = min(64, deg - c0);
        int T = (cnt - half + 1) >> 1;  // edges this half processes (j = 2t+half)
        int t = 0;
        for (; t + 8 <= T; t += 8) {
            float w[8]; uint off[8]; uint2 v[8];
#pragma unroll
            for (int b = 0; b < 8; b++) {
                int j = 2 * (t + b) + half;
                w[b] = coef[j];
                off[b] = soff[j];
            }
#pragma unroll
            for (int b = 0; b < 8; b++)
                v[b] = *(const uint2*)(hbase + off[b]);
#pragma unroll
            for (int b = 0; b < 8; b++) {
                a0 = fmaf(w[b], bfbits2f(v[b].x << 16), a0);
                a1 = fmaf(w[b], bfbits2f(v[b].x & 0xffff0000u), a1);
                a2 = fmaf(w[b], bfbits2f(v[b].y << 16), a2);
                a3 = fmaf(w[b], bfbits2f(v[b].y & 0xffff0000u), a3);
            }
        }
        for (; t < T; t++) {
            int j = 2 * t + half;
            float w = coef[j];
            uint2 v = *(const uint2*)(hbase + soff[j]);
            a0 = fmaf(w, bfbits2f(v.x << 16), a0);
            a1 = fmaf(w, bfbits2f(v.x & 0xffff0000u), a1);
            a2 = fmaf(w, bfbits2f(v.y << 16), a2);
            a3 = fmaf(w, bfbits2f(v.y & 0xffff0000u), a3);
        }
        __builtin_amdgcn_wave_barrier();
    }

    // Merge halves, bias + ReLU, bf16 write (32 lanes x 8B per node)
    a0 += __shfl_xor(a0, 32, 64);
    a1 += __shfl_xor(a1, 32, 64);
    a2 += __shfl_xor(a2, 32, 64);
    a3 += __shfl_xor(a3, 32, 64);
    if (half == 0) {
        float4 bv = *(const float4*)&bias[c4];
        float o0 = fmaxf(a0 + bv.x, 0.f);
        float o1 = fmaxf(a1 + bv.y, 0.f);
        float o2 = fmaxf(a2 + bv.z, 0.f);
        float o3 = fmaxf(a3 + bv.w, 0.f);
        uint2 pk;
        pk.x = (uint)f2bf(o0) | ((uint)f2bf(o1) << 16);
        pk.y = (uint)f2bf(o2) | ((uint)f2bf(o3) << 16);
        *(uint2*)&outbf[(size_t)n * HID + c4] = pk;
    }
}

// ---------------------------------------------------------------------------
// Mean pool per graph (two-stage, bf16 input) + classifier
// ---------------------------------------------------------------------------
__global__ __launch_bounds__(128) void pool_partial(const ushort* __restrict__ h,
                                                    const int* __restrict__ gstart,
                                                    float* __restrict__ pool) {
    int g = blockIdx.x;
    int slice = blockIdx.y;
    int d = threadIdx.x;
    int beg = gstart[g], end = gstart[g + 1];
    float acc = 0.f;
    for (int i = beg + slice; i < end; i += 16)
        acc += bfbits2f(((uint)h[(size_t)i * HID + d]) << 16);
    atomicAdd(&pool[g * HID + d], acc);
}

__global__ __launch_bounds__(128) void classify(const float* __restrict__ pool,
                                                const int* __restrict__ gstart,
                                                const float* __restrict__ Wc,
                                                const float* __restrict__ bc,
                                                float* __restrict__ out) {
    int g = blockIdx.x;
    int d = threadIdx.x;
    float cnt = (float)(gstart[g + 1] - gstart[g]);
    float pooled = pool[g * HID + d] / fmaxf(cnt, 1.f);
    float p = pooled * Wc[d];
    __shared__ float red[2];
    for (int o = 32; o; o >>= 1) p += __shfl_xor(p, o, 64);
    if ((d & 63) == 0) red[d >> 6] = p;
    __syncthreads();
    if (d == 0) {
        float t = red[0] + red[1] + bc[0];
        out[g] = 1.f / (1.f + expf(-t));
    }
}

// ---------------------------------------------------------------------------
extern "C" void kernel_launch(void* const* d_in, const int* in_sizes, int n_in,
                              void* d_out, int out_size, void* d_ws, size_t ws_size,
                              hipStream_t stream) {
    const float* x     = (const float*)d_in[0];
    const int*   ei    = (const int*)d_in[1];
    const int*   batch = (const int*)d_in[2];
    const float* W1    = (const float*)d_in[3];
    const float* as1   = (const float*)d_in[4];
    const float* ad1   = (const float*)d_in[5];
    const float* b1    = (const float*)d_in[6];
    const float* W2    = (const float*)d_in[7];
    const float* as2   = (const float*)d_in[8];
    const float* ad2   = (const float*)d_in[9];
    const float* b2    = (const float*)d_in[10];
    const float* Wc    = (const float*)d_in[11];
    const float* bc    = (const float*)d_in[12];
    float* out = (float*)d_out;

    char* p = (char*)d_ws;
    auto alloc = [&](size_t bytes) {
        void* r = (void*)p;
        p += (bytes + 255) & ~(size_t)255;
        return r;
    };
    ushort* h0     = (ushort*)alloc((size_t)N_NODES * HID * 2);   // gemm1 out / agg2 out
    ushort* h1     = (ushort*)alloc((size_t)N_NODES * HID * 2);   // agg1 out
    ushort* h2     = (ushort*)alloc((size_t)N_NODES * HID * 2);   // gemm2 out
    float*  alS    = (float*)alloc((size_t)N_NODES * 4);
    float*  alD    = (float*)alloc((size_t)N_NODES * 4);
    uint*   staged = (uint*)alloc((size_t)NBKT * CAPB * 4);       // 4.8 MB
    ushort* csr    = (ushort*)alloc((size_t)E_TOT * 2);           // 1.7 MB
    int*    rstart = (int*)alloc((size_t)(N_NODES + 1) * 4);
    int*    bbase  = (int*)alloc((NBKT + 1) * 4);
    int*    gcur   = (int*)alloc((NBKT + 1) * 4);
    int*    gstart = (int*)alloc((N_GRAPHS + 1) * 4);
    float*  pool   = (float*)alloc(N_GRAPHS * HID * 4);
    ushort* Wt1    = (ushort*)alloc((size_t)128 * 256 * 2);
    ushort* Wt2    = (ushort*)alloc((size_t)128 * 128 * 2);

    const int* edge_src = ei;
    const int* edge_dst = ei + N_EDGES;

    hipMemsetAsync(gcur, 0, (NBKT + 1) * 4, stream);
    hipMemsetAsync(pool, 0, (size_t)N_GRAPHS * HID * 4, stream);

    // Weight prep + radix-partition CSR build
    convW<256><<<(256 * 128 + 255) / 256, 256, 0, stream>>>(W1, Wt1);
    convW<128><<<(128 * 128 + 255) / 256, 256, 0, stream>>>(W2, Wt2);
    bin_scatter<<<NB3, 256, 0, stream>>>(edge_src, edge_dst, gcur, staged);
    bucket_scan<<<1, 256, 0, stream>>>(gcur, bbase, rstart);
    bucket_build<<<NBKT, 256, 0, stream>>>(staged, bbase, rstart, csr);
    graph_bounds<<<(N_NODES + 255) / 256, 256, 0, stream>>>(batch, gstart);

    // Layer 1
    gemm_mfma<256, false><<<(N_NODES + 63) / 64, 256, 0, stream>>>(
        x, Wt1, h0, as1, ad1, alS, alD, N_NODES);
    gat_aggregate<<<N_NODES / 4, 256, 0, stream>>>(h0, alS, alD, rstart, csr, b1, h1);

    // Layer 2
    gemm_mfma<128, true><<<(N_NODES + 63) / 64, 256, 0, stream>>>(
        h1, Wt2, h2, as2, ad2, alS, alD, N_NODES);
    gat_aggregate<<<N_NODES / 4, 256, 0, stream>>>(h2, alS, alD, rstart, csr, b2, h0);

    // Pool + classify
    pool_partial<<<dim3(N_GRAPHS, 16), HID, 0, stream>>>(h0, gstart, pool);
    classify<<<N_GRAPHS, HID, 0, stream>>>(pool, gstart, Wc, bc, out);
}